// Round 2
// baseline (2440.663 us; speedup 1.0000x reference)
//
#include <hip/hip_runtime.h>
#include <hip/hip_bf16.h>

#define HID 128
#define TILE_R 64
#define KT 64
#define IN_LD 68    // 64 + 4 pad, keeps float4 alignment
#define W_LD 132    // 128 + 4 pad

// ---------------- gather: h[i] = emb[x[i]] ----------------
__global__ __launch_bounds__(256) void gather_kernel(
    const float* __restrict__ emb, const int* __restrict__ x,
    float* __restrict__ h, int N) {
  int tid = blockIdx.x * blockDim.x + threadIdx.x;  // N*32 threads (float4 each)
  if (tid >= N * 32) return;
  int r = tid >> 5, j = (tid & 31) * 4;
  int s = x[r];
  *(float4*)&h[(size_t)r * HID + j] = *(const float4*)&emb[(size_t)s * HID + j];
}

// ---------------- scatter: agg[dst] += h[src]; cnt[dst]++ ----------------
__global__ __launch_bounds__(256) void scatter_kernel(
    const float* __restrict__ h, const int* __restrict__ src,
    const int* __restrict__ dst, float* __restrict__ agg,
    int* __restrict__ cnt, int E) {
  int t = threadIdx.x;
  int e = blockIdx.x * 8 + (t >> 5);
  if (e >= E) return;
  int lane = t & 31;
  int s = src[e], d = dst[e];
  float4 v = *(const float4*)&h[(size_t)s * HID + lane * 4];
  float* a = &agg[(size_t)d * HID + lane * 4];
  unsafeAtomicAdd(a + 0, v.x);
  unsafeAtomicAdd(a + 1, v.y);
  unsafeAtomicAdd(a + 2, v.z);
  unsafeAtomicAdd(a + 3, v.w);
  if (lane == 0) atomicAdd(&cnt[d], 1);
}

// ---------------- fused SAGE transform ----------------
// out[r][c] = relu( sum_k (agg[r][k]/max(cnt[r],1)) * Wl[c][k]
//                 + sum_k h[r][k] * Wr[c][k] + bias[c] )
// Row-partitioned per block -> in-place out==h or out==agg is safe.
__global__ __launch_bounds__(256) void gemm_kernel(
    const float* __restrict__ agg, const int* __restrict__ cnt,
    const float* __restrict__ h, const float* __restrict__ Wl,
    const float* __restrict__ Wr, const float* __restrict__ bias,
    float* __restrict__ out, int N) {
  __shared__ float in_s[TILE_R * IN_LD];  // 17408 B
  __shared__ float w_s[KT * W_LD];        // 33792 B
  const int t = threadIdx.x;
  const int rowBase = blockIdx.x * TILE_R;
  const int c4 = (t & 31) * 4;   // 4 output columns
  const int rb = (t >> 5) * 8;   // 8 output rows

  float4 acc[8];
#pragma unroll
  for (int i = 0; i < 8; i++) acc[i] = make_float4(0.f, 0.f, 0.f, 0.f);

  for (int kt = 0; kt < 4; kt++) {
    const bool meanHalf = (kt < 2);
    const int koff = (kt & 1) * 64;
    const float* src = meanHalf ? agg : h;
    const float* W = meanHalf ? Wl : Wr;
    __syncthreads();  // previous tile fully consumed before overwrite
    // stage input tile: 64 rows x 64 k
#pragma unroll
    for (int it = 0; it < 4; it++) {
      int idx = t + it * 256;     // 0..1023
      int r = idx >> 4;           // 0..63
      int k4 = (idx & 15) * 4;    // 0..60
      int rg = rowBase + r;
      float4 v = make_float4(0.f, 0.f, 0.f, 0.f);
      if (rg < N) {
        v = *(const float4*)&src[(size_t)rg * HID + koff + k4];
        if (meanHalf) {
          int c = cnt[rg];
          float inv = 1.0f / (float)(c > 1 ? c : 1);
          v.x *= inv; v.y *= inv; v.z *= inv; v.w *= inv;
        }
      }
      *(float4*)&in_s[r * IN_LD + k4] = v;
    }
    // stage W transposed: w_s[kl][c] = W[c][koff+kl]
#pragma unroll
    for (int it = 0; it < 8; it++) {
      int idx = t + it * 256;     // 0..2047
      int c = idx >> 4;           // 0..127
      int k4 = (idx & 15) * 4;
      float4 v = *(const float4*)&W[(size_t)c * HID + koff + k4];
      w_s[(k4 + 0) * W_LD + c] = v.x;
      w_s[(k4 + 1) * W_LD + c] = v.y;
      w_s[(k4 + 2) * W_LD + c] = v.z;
      w_s[(k4 + 3) * W_LD + c] = v.w;
    }
    __syncthreads();
#pragma unroll 8
    for (int kl = 0; kl < KT; kl++) {
      float4 w = *(const float4*)&w_s[kl * W_LD + c4];
#pragma unroll
      for (int i = 0; i < 8; i++) {
        float a = in_s[(rb + i) * IN_LD + kl];
        acc[i].x += a * w.x; acc[i].y += a * w.y;
        acc[i].z += a * w.z; acc[i].w += a * w.w;
      }
    }
  }
  float4 b = *(const float4*)&bias[c4];
#pragma unroll
  for (int i = 0; i < 8; i++) {
    int rg = rowBase + rb + i;
    if (rg < N) {
      float4 o;
      o.x = fmaxf(acc[i].x + b.x, 0.f);
      o.y = fmaxf(acc[i].y + b.y, 0.f);
      o.z = fmaxf(acc[i].z + b.z, 0.f);
      o.w = fmaxf(acc[i].w + b.w, 0.f);
      *(float4*)&out[(size_t)rg * HID + c4] = o;
    }
  }
}

extern "C" void kernel_launch(void* const* d_in, const int* in_sizes, int n_in,
                              void* d_out, int out_size, void* d_ws, size_t ws_size,
                              hipStream_t stream) {
  const int* x = (const int*)d_in[0];
  const int* ei = (const int*)d_in[1];
  const float* emb = (const float*)d_in[2];
  const float* Wl1 = (const float*)d_in[3];
  const float* bl1 = (const float*)d_in[4];
  const float* Wr1 = (const float*)d_in[5];
  const float* Wl2 = (const float*)d_in[6];
  const float* bl2 = (const float*)d_in[7];
  const float* Wr2 = (const float*)d_in[8];
  float* out = (float*)d_out;

  const int N = in_sizes[0];
  const int E = in_sizes[1] / 2;
  const int* srcI = ei;
  const int* dstI = ei + E;

  float* h = (float*)d_ws;                                    // N*128 f32
  int* cnt = (int*)((char*)d_ws + (size_t)N * HID * sizeof(float));  // N i32
  float* agg = out;  // d_out doubles as the aggregation buffer

  const size_t aggBytes = (size_t)N * HID * sizeof(float);
  const int gatherBlocks = (N * 32 + 255) / 256;
  const int scatterBlocks = (E + 7) / 8;
  const int gemmBlocks = (N + TILE_R - 1) / TILE_R;

  // ---- layer 1 ----
  hipMemsetAsync(agg, 0, aggBytes, stream);
  hipMemsetAsync(cnt, 0, (size_t)N * sizeof(int), stream);
  gather_kernel<<<gatherBlocks, 256, 0, stream>>>(emb, x, h, N);
  scatter_kernel<<<scatterBlocks, 256, 0, stream>>>(h, srcI, dstI, agg, cnt, E);
  // writes h in place (h2 overwrites h1; row-partitioned => safe)
  gemm_kernel<<<gemmBlocks, 256, 0, stream>>>(agg, cnt, h, Wl1, Wr1, bl1, h, N);

  // ---- layer 2 ----
  hipMemsetAsync(agg, 0, aggBytes, stream);
  hipMemsetAsync(cnt, 0, (size_t)N * sizeof(int), stream);
  scatter_kernel<<<scatterBlocks, 256, 0, stream>>>(h, srcI, dstI, agg, cnt, E);
  // out == agg in-place: agg rows are only read during staging (own rows),
  // all reads complete before epilogue writes => safe
  gemm_kernel<<<gemmBlocks, 256, 0, stream>>>(agg, cnt, h, Wl2, Wr2, bl2, out, N);
}

// Round 3
// 549.180 us; speedup vs baseline: 4.4442x; 4.4442x over previous
//
#include <hip/hip_runtime.h>

#define HID 128
#define TILE_R 64
#define KT 64
#define IN_LD 68    // 64 + 4 pad
#define W_LD 132    // 128 + 4 pad

// ---------------- gather: h[i] = emb[x[i]] ----------------
__global__ __launch_bounds__(256) void gather_kernel(
    const float* __restrict__ emb, const int* __restrict__ x,
    float* __restrict__ h, int N) {
  int tid = blockIdx.x * blockDim.x + threadIdx.x;
  if (tid >= N * 32) return;
  int r = tid >> 5, j = (tid & 31) * 4;
  int s = x[r];
  *(float4*)&h[(size_t)r * HID + j] = *(const float4*)&emb[(size_t)s * HID + j];
}

// ---------------- CSR build ----------------
__global__ __launch_bounds__(256) void degcount_kernel(
    const int* __restrict__ dst, int* __restrict__ deg, int E) {
  int e = blockIdx.x * 256 + threadIdx.x;
  if (e < E) atomicAdd(&deg[dst[e]], 1);
}

// per-1024-chunk exclusive scan; block total -> sums[b]
__global__ __launch_bounds__(256) void scan1_kernel(
    const int* __restrict__ deg, int* __restrict__ offsets,
    int* __restrict__ sums, int N) {
  __shared__ int s[256];
  int b = blockIdx.x, t = threadIdx.x;
  int base = b * 1024 + t * 4;
  int v0 = 0, v1 = 0, v2 = 0, v3 = 0;
  if (base + 0 < N) v0 = deg[base + 0];
  if (base + 1 < N) v1 = deg[base + 1];
  if (base + 2 < N) v2 = deg[base + 2];
  if (base + 3 < N) v3 = deg[base + 3];
  int mySum = v0 + v1 + v2 + v3;
  s[t] = mySum;
  __syncthreads();
  for (int off = 1; off < 256; off <<= 1) {
    int v = (t >= off) ? s[t - off] : 0;
    __syncthreads();
    s[t] += v;
    __syncthreads();
  }
  int excl = s[t] - mySum;
  if (t == 255) sums[b] = s[255];
  if (base + 0 < N) offsets[base + 0] = excl;
  if (base + 1 < N) offsets[base + 1] = excl + v0;
  if (base + 2 < N) offsets[base + 2] = excl + v0 + v1;
  if (base + 3 < N) offsets[base + 3] = excl + v0 + v1 + v2;
}

// exclusive scan of block sums (nb <= 256)
__global__ __launch_bounds__(256) void scan2_kernel(int* __restrict__ sums, int nb) {
  __shared__ int s[256];
  int t = threadIdx.x;
  int v = (t < nb) ? sums[t] : 0;
  s[t] = v;
  __syncthreads();
  for (int off = 1; off < 256; off <<= 1) {
    int x = (t >= off) ? s[t - off] : 0;
    __syncthreads();
    s[t] += x;
    __syncthreads();
  }
  if (t < nb) sums[t] = s[t] - v;
}

__global__ __launch_bounds__(256) void scan3_kernel(
    int* __restrict__ offsets, const int* __restrict__ sums, int N, int E) {
  int i = blockIdx.x * 256 + threadIdx.x;
  if (i < N) offsets[i] += sums[i >> 10];
  else if (i == N) offsets[N] = E;
}

__global__ __launch_bounds__(256) void fill_kernel(
    const int* __restrict__ src, const int* __restrict__ dst,
    int* __restrict__ cursor, int* __restrict__ csr, int E) {
  int e = blockIdx.x * 256 + threadIdx.x;
  if (e >= E) return;
  int d = dst[e];
  int pos = atomicAdd(&cursor[d], 1);
  csr[pos] = src[e];
}

// ---------------- aggregate: mean[i] = sum_{j->i} h[j] / max(deg,1) ----------------
// one 64-lane wave per node, float2 per lane (512 B per edge row)
__global__ __launch_bounds__(256) void aggregate_kernel(
    const float* __restrict__ h, const int* __restrict__ offsets,
    const int* __restrict__ csr, float* __restrict__ mean, int N) {
  int t = threadIdx.x;
  int node = blockIdx.x * 4 + (t >> 6);
  if (node >= N) return;
  int lane = t & 63;
  int o0 = offsets[node], o1 = offsets[node + 1];
  float accx = 0.f, accy = 0.f;
  for (int e = o0; e < o1; e++) {
    int s = csr[e];
    float2 v = *(const float2*)&h[(size_t)s * HID + lane * 2];
    accx += v.x; accy += v.y;
  }
  int d = o1 - o0;
  float inv = 1.0f / (float)(d > 1 ? d : 1);
  float2 r; r.x = accx * inv; r.y = accy * inv;
  *(float2*)&mean[(size_t)node * HID + lane * 2] = r;
}

// ---------------- fused SAGE transform ----------------
// out[r][c] = relu( sum_k mean[r][k]*Wl[c][k] + sum_k h[r][k]*Wr[c][k] + bias[c] )
// Row-partitioned per block -> in-place out==h or out==mean is safe.
__global__ __launch_bounds__(256) void gemm_kernel(
    const float* __restrict__ mean, const float* __restrict__ h,
    const float* __restrict__ Wl, const float* __restrict__ Wr,
    const float* __restrict__ bias, float* __restrict__ out, int N) {
  __shared__ float in_s[TILE_R * IN_LD];
  __shared__ float w_s[KT * W_LD];
  const int t = threadIdx.x;
  const int rowBase = blockIdx.x * TILE_R;
  const int c4 = (t & 31) * 4;
  const int rb = (t >> 5) * 8;

  float4 acc[8];
#pragma unroll
  for (int i = 0; i < 8; i++) acc[i] = make_float4(0.f, 0.f, 0.f, 0.f);

  for (int kt = 0; kt < 4; kt++) {
    const bool meanHalf = (kt < 2);
    const int koff = (kt & 1) * 64;
    const float* src = meanHalf ? mean : h;
    const float* W = meanHalf ? Wl : Wr;
    __syncthreads();
#pragma unroll
    for (int it = 0; it < 4; it++) {
      int idx = t + it * 256;
      int r = idx >> 4;
      int k4 = (idx & 15) * 4;
      int rg = rowBase + r;
      float4 v = make_float4(0.f, 0.f, 0.f, 0.f);
      if (rg < N) v = *(const float4*)&src[(size_t)rg * HID + koff + k4];
      *(float4*)&in_s[r * IN_LD + k4] = v;
    }
#pragma unroll
    for (int it = 0; it < 8; it++) {
      int idx = t + it * 256;
      int c = idx >> 4;
      int k4 = (idx & 15) * 4;
      float4 v = *(const float4*)&W[(size_t)c * HID + koff + k4];
      w_s[(k4 + 0) * W_LD + c] = v.x;
      w_s[(k4 + 1) * W_LD + c] = v.y;
      w_s[(k4 + 2) * W_LD + c] = v.z;
      w_s[(k4 + 3) * W_LD + c] = v.w;
    }
    __syncthreads();
#pragma unroll 8
    for (int kl = 0; kl < KT; kl++) {
      float4 w = *(const float4*)&w_s[kl * W_LD + c4];
#pragma unroll
      for (int i = 0; i < 8; i++) {
        float a = in_s[(rb + i) * IN_LD + kl];
        acc[i].x += a * w.x; acc[i].y += a * w.y;
        acc[i].z += a * w.z; acc[i].w += a * w.w;
      }
    }
  }
  float4 b = *(const float4*)&bias[c4];
#pragma unroll
  for (int i = 0; i < 8; i++) {
    int rg = rowBase + rb + i;
    if (rg < N) {
      float4 o;
      o.x = fmaxf(acc[i].x + b.x, 0.f);
      o.y = fmaxf(acc[i].y + b.y, 0.f);
      o.z = fmaxf(acc[i].z + b.z, 0.f);
      o.w = fmaxf(acc[i].w + b.w, 0.f);
      *(float4*)&out[(size_t)rg * HID + c4] = o;
    }
  }
}

extern "C" void kernel_launch(void* const* d_in, const int* in_sizes, int n_in,
                              void* d_out, int out_size, void* d_ws, size_t ws_size,
                              hipStream_t stream) {
  const int* x = (const int*)d_in[0];
  const int* ei = (const int*)d_in[1];
  const float* emb = (const float*)d_in[2];
  const float* Wl1 = (const float*)d_in[3];
  const float* bl1 = (const float*)d_in[4];
  const float* Wr1 = (const float*)d_in[5];
  const float* Wl2 = (const float*)d_in[6];
  const float* bl2 = (const float*)d_in[7];
  const float* Wr2 = (const float*)d_in[8];
  float* out = (float*)d_out;

  const int N = in_sizes[0];
  const int E = in_sizes[1] / 2;
  const int* srcI = ei;
  const int* dstI = ei + E;

  // workspace layout
  char* p = (char*)d_ws;
  float* h = (float*)p;           p += (size_t)N * HID * sizeof(float);
  int* deg = (int*)p;             p += (size_t)((N + 3) & ~3) * sizeof(int);
  int* offsets = (int*)p;         p += (size_t)((N + 4) & ~3) * sizeof(int);
  int* cursor = (int*)p;          p += (size_t)((N + 3) & ~3) * sizeof(int);
  int* csr = (int*)p;             p += (size_t)((E + 3) & ~3) * sizeof(int);
  int* sums = (int*)p;            p += 256 * sizeof(int);

  float* mean = out;  // d_out doubles as the mean buffer

  const int nScanBlocks = (N + 1023) / 1024;  // 98 for N=100k (<=256 required)
  const int eBlocks = (E + 255) / 256;
  const int gemmBlocks = (N + TILE_R - 1) / TILE_R;

  // ---- CSR build (once, reused by both layers) ----
  hipMemsetAsync(deg, 0, (size_t)N * sizeof(int), stream);
  gather_kernel<<<(N * 32 + 255) / 256, 256, 0, stream>>>(emb, x, h, N);
  degcount_kernel<<<eBlocks, 256, 0, stream>>>(dstI, deg, E);
  scan1_kernel<<<nScanBlocks, 256, 0, stream>>>(deg, offsets, sums, N);
  scan2_kernel<<<1, 256, 0, stream>>>(sums, nScanBlocks);
  scan3_kernel<<<(N + 256) / 256, 256, 0, stream>>>(offsets, sums, N, E);
  hipMemcpyAsync(cursor, offsets, (size_t)N * sizeof(int),
                 hipMemcpyDeviceToDevice, stream);
  fill_kernel<<<eBlocks, 256, 0, stream>>>(srcI, dstI, cursor, csr, E);

  // ---- layer 1 ----
  aggregate_kernel<<<(N + 3) / 4, 256, 0, stream>>>(h, offsets, csr, mean, N);
  gemm_kernel<<<gemmBlocks, 256, 0, stream>>>(mean, h, Wl1, Wr1, bl1, h, N);

  // ---- layer 2 ----
  aggregate_kernel<<<(N + 3) / 4, 256, 0, stream>>>(h, offsets, csr, mean, N);
  gemm_kernel<<<gemmBlocks, 256, 0, stream>>>(mean, h, Wl2, Wr2, bl2, out, N);
}

// Round 4
// 429.222 us; speedup vs baseline: 5.6863x; 1.2795x over previous
//
#include <hip/hip_runtime.h>

#define HID 128

typedef unsigned short ushort_t;
typedef unsigned int uint_t;
typedef float f32x4 __attribute__((ext_vector_type(4)));
typedef short s16x8 __attribute__((ext_vector_type(8)));

__device__ __forceinline__ ushort_t f2bf(float f) {
  uint_t u = __float_as_uint(f);
  uint_t r = (u + 0x7FFFu + ((u >> 16) & 1u)) >> 16;  // RNE
  return (ushort_t)r;
}
__device__ __forceinline__ float bfLo(uint_t v) { return __uint_as_float(v << 16); }
__device__ __forceinline__ float bfHi(uint_t v) { return __uint_as_float(v & 0xFFFF0000u); }

// ---------------- gather: hb[i] = bf16(emb[x[i]]) ----------------
__global__ __launch_bounds__(256) void gather_bf16_kernel(
    const float* __restrict__ emb, const int* __restrict__ x,
    ushort_t* __restrict__ hb, int N) {
  int tid = blockIdx.x * blockDim.x + threadIdx.x;
  if (tid >= N * 32) return;
  int r = tid >> 5, j = (tid & 31) * 4;
  int s = x[r];
  float4 v = *(const float4*)&emb[(size_t)s * HID + j];
  uint2 p;
  p.x = (uint_t)f2bf(v.x) | ((uint_t)f2bf(v.y) << 16);
  p.y = (uint_t)f2bf(v.z) | ((uint_t)f2bf(v.w) << 16);
  *(uint2*)&hb[(size_t)r * HID + j] = p;
}

// ---------------- weights f32 -> bf16 (4 matrices of 128x128) ----------------
__global__ __launch_bounds__(256) void wconv_kernel(
    const float* __restrict__ Wl1, const float* __restrict__ Wr1,
    const float* __restrict__ Wl2, const float* __restrict__ Wr2,
    ushort_t* __restrict__ wb) {
  int i = blockIdx.x * 256 + threadIdx.x;  // 0..65535
  const float* srcs[4] = {Wl1, Wr1, Wl2, Wr2};
  int m = i >> 14, off = i & 16383;
  wb[i] = f2bf(srcs[m][off]);
}

// ---------------- CSR build ----------------
__global__ __launch_bounds__(256) void degcount_kernel(
    const int* __restrict__ dst, int* __restrict__ deg, int E) {
  int e = blockIdx.x * 256 + threadIdx.x;
  if (e < E) atomicAdd(&deg[dst[e]], 1);
}

__global__ __launch_bounds__(256) void scan1_kernel(
    const int* __restrict__ deg, int* __restrict__ offsets,
    int* __restrict__ sums, int N) {
  __shared__ int s[256];
  int b = blockIdx.x, t = threadIdx.x;
  int base = b * 1024 + t * 4;
  int v0 = 0, v1 = 0, v2 = 0, v3 = 0;
  if (base + 0 < N) v0 = deg[base + 0];
  if (base + 1 < N) v1 = deg[base + 1];
  if (base + 2 < N) v2 = deg[base + 2];
  if (base + 3 < N) v3 = deg[base + 3];
  int mySum = v0 + v1 + v2 + v3;
  s[t] = mySum;
  __syncthreads();
  for (int off = 1; off < 256; off <<= 1) {
    int v = (t >= off) ? s[t - off] : 0;
    __syncthreads();
    s[t] += v;
    __syncthreads();
  }
  int excl = s[t] - mySum;
  if (t == 255) sums[b] = s[255];
  if (base + 0 < N) offsets[base + 0] = excl;
  if (base + 1 < N) offsets[base + 1] = excl + v0;
  if (base + 2 < N) offsets[base + 2] = excl + v0 + v1;
  if (base + 3 < N) offsets[base + 3] = excl + v0 + v1 + v2;
}

__global__ __launch_bounds__(256) void scan2_kernel(int* __restrict__ sums, int nb) {
  __shared__ int s[256];
  int t = threadIdx.x;
  int v = (t < nb) ? sums[t] : 0;
  s[t] = v;
  __syncthreads();
  for (int off = 1; off < 256; off <<= 1) {
    int x = (t >= off) ? s[t - off] : 0;
    __syncthreads();
    s[t] += x;
    __syncthreads();
  }
  if (t < nb) sums[t] = s[t] - v;
}

__global__ __launch_bounds__(256) void scan3_kernel(
    int* __restrict__ offsets, const int* __restrict__ sums, int N, int E) {
  int i = blockIdx.x * 256 + threadIdx.x;
  if (i < N) offsets[i] += sums[i >> 10];
  else if (i == N) offsets[N] = E;
}

__global__ __launch_bounds__(256) void fill_kernel(
    const int* __restrict__ src, const int* __restrict__ dst,
    int* __restrict__ cursor, int* __restrict__ csr, int E) {
  int e = blockIdx.x * 256 + threadIdx.x;
  if (e >= E) return;
  int d = dst[e];
  int pos = atomicAdd(&cursor[d], 1);
  csr[pos] = src[e];
}

// ---------------- aggregate (bf16 in, f32 acc, bf16 out) ----------------
// one 64-lane wave per node; lane handles 2 features (uint load = 2 bf16)
__global__ __launch_bounds__(256) void aggregate_kernel(
    const ushort_t* __restrict__ hb, const int* __restrict__ offsets,
    const int* __restrict__ csr, ushort_t* __restrict__ meanb, int N) {
  int t = threadIdx.x;
  int node = blockIdx.x * 4 + (t >> 6);
  if (node >= N) return;
  int lane = t & 63;
  int o0 = offsets[node], o1 = offsets[node + 1];
  float ax = 0.f, ay = 0.f;
  for (int e = o0; e < o1; e++) {
    int s = csr[e];
    uint_t v = *(const uint_t*)&hb[(size_t)s * HID + lane * 2];
    ax += bfLo(v);
    ay += bfHi(v);
  }
  int d = o1 - o0;
  float inv = 1.0f / (float)(d > 1 ? d : 1);
  uint_t p = (uint_t)f2bf(ax * inv) | ((uint_t)f2bf(ay * inv) << 16);
  *(uint_t*)&meanb[(size_t)node * HID + lane * 2] = p;
}

// ---------------- MFMA GEMM: out[r][c] = relu(mean@Wl^T + h@Wr^T + b) ----------------
// Wave computes 32 rows x 128 cols. No LDS: A and B fragments of
// mfma_f32_16x16x32_bf16 are contiguous 16B/lane from row-major storage:
//   A[m=lane&15][k=quad*8+j]  <- input row (rowBase+m), 16B at k-offset
//   B[k][n]: n=lane&15        <- W row n (out = in @ W^T), 16B at k-offset
// C/D: col=lane&15, row=quad*4+reg.
// In-place out==hb safe: wave reads/writes only its own 32 rows (N%32==0).
__global__ __launch_bounds__(256) void mfma_gemm_kernel(
    const ushort_t* __restrict__ meanb, const ushort_t* __restrict__ hb,
    const ushort_t* __restrict__ Wlb, const ushort_t* __restrict__ Wrb,
    const float* __restrict__ bias, float* __restrict__ outF,
    ushort_t* __restrict__ outB, int N, int outIsBf16) {
  const int wave = threadIdx.x >> 6;
  const int lane = threadIdx.x & 63;
  const int rowBase = (blockIdx.x * 4 + wave) * 32;
  if (rowBase >= N) return;
  const int l15 = lane & 15;
  const int quad = lane >> 4;

  int r0 = rowBase + l15;       if (r0 >= N) r0 = N - 1;
  int r1 = rowBase + 16 + l15;  if (r1 >= N) r1 = N - 1;

  f32x4 acc[2][8];
#pragma unroll
  for (int mt = 0; mt < 2; mt++)
#pragma unroll
    for (int nt = 0; nt < 8; nt++) acc[mt][nt] = (f32x4){0.f, 0.f, 0.f, 0.f};

#pragma unroll
  for (int half = 0; half < 2; half++) {
    const ushort_t* A = half ? hb : meanb;
    const ushort_t* W = half ? Wrb : Wlb;
#pragma unroll
    for (int ks = 0; ks < 4; ks++) {
      const int koff = ks * 32 + quad * 8;
      s16x8 a0 = *(const s16x8*)&A[(size_t)r0 * HID + koff];
      s16x8 a1 = *(const s16x8*)&A[(size_t)r1 * HID + koff];
      s16x8 b[8];
#pragma unroll
      for (int nt = 0; nt < 8; nt++)
        b[nt] = *(const s16x8*)&W[(size_t)(nt * 16 + l15) * HID + koff];
#pragma unroll
      for (int nt = 0; nt < 8; nt++) {
        acc[0][nt] = __builtin_amdgcn_mfma_f32_16x16x32_bf16(a0, b[nt], acc[0][nt], 0, 0, 0);
        acc[1][nt] = __builtin_amdgcn_mfma_f32_16x16x32_bf16(a1, b[nt], acc[1][nt], 0, 0, 0);
      }
    }
  }

#pragma unroll
  for (int mt = 0; mt < 2; mt++) {
#pragma unroll
    for (int nt = 0; nt < 8; nt++) {
      int col = nt * 16 + l15;
      float bv = bias[col];
#pragma unroll
      for (int r = 0; r < 4; r++) {
        int row = rowBase + mt * 16 + quad * 4 + r;
        if (row < N) {
          float v = fmaxf(acc[mt][nt][r] + bv, 0.f);
          if (outIsBf16) outB[(size_t)row * HID + col] = f2bf(v);
          else           outF[(size_t)row * HID + col] = v;
        }
      }
    }
  }
}

extern "C" void kernel_launch(void* const* d_in, const int* in_sizes, int n_in,
                              void* d_out, int out_size, void* d_ws, size_t ws_size,
                              hipStream_t stream) {
  const int* x = (const int*)d_in[0];
  const int* ei = (const int*)d_in[1];
  const float* emb = (const float*)d_in[2];
  const float* Wl1 = (const float*)d_in[3];
  const float* bl1 = (const float*)d_in[4];
  const float* Wr1 = (const float*)d_in[5];
  const float* Wl2 = (const float*)d_in[6];
  const float* bl2 = (const float*)d_in[7];
  const float* Wr2 = (const float*)d_in[8];
  float* out = (float*)d_out;

  const int N = in_sizes[0];
  const int E = in_sizes[1] / 2;
  const int* srcI = ei;
  const int* dstI = ei + E;

  // workspace layout
  char* p = (char*)d_ws;
  ushort_t* hb = (ushort_t*)p;    p += (size_t)N * HID * sizeof(ushort_t);
  ushort_t* meanb = (ushort_t*)p; p += (size_t)N * HID * sizeof(ushort_t);
  ushort_t* wb = (ushort_t*)p;    p += (size_t)4 * 16384 * sizeof(ushort_t);
  int* deg = (int*)p;             p += (size_t)((N + 3) & ~3) * sizeof(int);
  int* offsets = (int*)p;         p += (size_t)((N + 4) & ~3) * sizeof(int);
  int* cursor = (int*)p;          p += (size_t)((N + 3) & ~3) * sizeof(int);
  int* csr = (int*)p;             p += (size_t)((E + 3) & ~3) * sizeof(int);
  int* sums = (int*)p;            p += 256 * sizeof(int);

  ushort_t* Wlb1 = wb;
  ushort_t* Wrb1 = wb + 16384;
  ushort_t* Wlb2 = wb + 32768;
  ushort_t* Wrb2 = wb + 49152;

  const int nScanBlocks = (N + 1023) / 1024;  // <=256 required
  const int eBlocks = (E + 255) / 256;
  const int gemmBlocks = (N + 127) / 128;     // 4 waves x 32 rows per block
  const int aggBlocks = (N + 3) / 4;

  // ---- CSR build + conversions ----
  hipMemsetAsync(deg, 0, (size_t)N * sizeof(int), stream);
  wconv_kernel<<<256, 256, 0, stream>>>(Wl1, Wr1, Wl2, Wr2, wb);
  gather_bf16_kernel<<<(N * 32 + 255) / 256, 256, 0, stream>>>(emb, x, hb, N);
  degcount_kernel<<<eBlocks, 256, 0, stream>>>(dstI, deg, E);
  scan1_kernel<<<nScanBlocks, 256, 0, stream>>>(deg, offsets, sums, N);
  scan2_kernel<<<1, 256, 0, stream>>>(sums, nScanBlocks);
  scan3_kernel<<<(N + 256) / 256, 256, 0, stream>>>(offsets, sums, N, E);
  hipMemcpyAsync(cursor, offsets, (size_t)N * sizeof(int),
                 hipMemcpyDeviceToDevice, stream);
  fill_kernel<<<eBlocks, 256, 0, stream>>>(srcI, dstI, cursor, csr, E);

  // ---- layer 1 ----
  aggregate_kernel<<<aggBlocks, 256, 0, stream>>>(hb, offsets, csr, meanb, N);
  mfma_gemm_kernel<<<gemmBlocks, 256, 0, stream>>>(meanb, hb, Wlb1, Wrb1, bl1,
                                                   nullptr, hb, N, 1);

  // ---- layer 2 ----
  aggregate_kernel<<<aggBlocks, 256, 0, stream>>>(hb, offsets, csr, meanb, N);
  mfma_gemm_kernel<<<gemmBlocks, 256, 0, stream>>>(meanb, hb, Wlb2, Wrb2, bl2,
                                                   out, nullptr, N, 0);
}

// Round 5
// 364.812 us; speedup vs baseline: 6.6902x; 1.1766x over previous
//
#include <hip/hip_runtime.h>

#define HID 128

typedef unsigned short ushort_t;
typedef unsigned int uint_t;
typedef float f32x4 __attribute__((ext_vector_type(4)));
typedef short s16x8 __attribute__((ext_vector_type(8)));

__device__ __forceinline__ ushort_t f2bf(float f) {
  uint_t u = __float_as_uint(f);
  uint_t r = (u + 0x7FFFu + ((u >> 16) & 1u)) >> 16;  // RNE
  return (ushort_t)r;
}
__device__ __forceinline__ float bfLo(uint_t v) { return __uint_as_float(v << 16); }
__device__ __forceinline__ float bfHi(uint_t v) { return __uint_as_float(v & 0xFFFF0000u); }

// ---------------- gather: hb[i] = bf16(emb[x[i]]) ----------------
__global__ __launch_bounds__(256) void gather_bf16_kernel(
    const float* __restrict__ emb, const int* __restrict__ x,
    ushort_t* __restrict__ hb, int N) {
  int tid = blockIdx.x * blockDim.x + threadIdx.x;
  if (tid >= N * 32) return;
  int r = tid >> 5, j = (tid & 31) * 4;
  int s = x[r];
  float4 v = *(const float4*)&emb[(size_t)s * HID + j];
  uint2 p;
  p.x = (uint_t)f2bf(v.x) | ((uint_t)f2bf(v.y) << 16);
  p.y = (uint_t)f2bf(v.z) | ((uint_t)f2bf(v.w) << 16);
  *(uint2*)&hb[(size_t)r * HID + j] = p;
}

// ---------------- weights f32 -> bf16 (4 matrices of 128x128) ----------------
__global__ __launch_bounds__(256) void wconv_kernel(
    const float* __restrict__ Wl1, const float* __restrict__ Wr1,
    const float* __restrict__ Wl2, const float* __restrict__ Wr2,
    ushort_t* __restrict__ wb) {
  int i = blockIdx.x * 256 + threadIdx.x;  // 0..65535
  const float* srcs[4] = {Wl1, Wr1, Wl2, Wr2};
  int m = i >> 14, off = i & 16383;
  wb[i] = f2bf(srcs[m][off]);
}

// ---------------- CSR build ----------------
__global__ __launch_bounds__(256) void degcount_kernel(
    const int* __restrict__ dst, int* __restrict__ deg, int E) {
  int e = blockIdx.x * 256 + threadIdx.x;
  if (e < E) atomicAdd(&deg[dst[e]], 1);
}

__global__ __launch_bounds__(256) void scan1_kernel(
    const int* __restrict__ deg, int* __restrict__ offsets,
    int* __restrict__ sums, int N) {
  __shared__ int s[256];
  int b = blockIdx.x, t = threadIdx.x;
  int base = b * 1024 + t * 4;
  int v0 = 0, v1 = 0, v2 = 0, v3 = 0;
  if (base + 0 < N) v0 = deg[base + 0];
  if (base + 1 < N) v1 = deg[base + 1];
  if (base + 2 < N) v2 = deg[base + 2];
  if (base + 3 < N) v3 = deg[base + 3];
  int mySum = v0 + v1 + v2 + v3;
  s[t] = mySum;
  __syncthreads();
  for (int off = 1; off < 256; off <<= 1) {
    int v = (t >= off) ? s[t - off] : 0;
    __syncthreads();
    s[t] += v;
    __syncthreads();
  }
  int excl = s[t] - mySum;
  if (t == 255) sums[b] = s[255];
  if (base + 0 < N) offsets[base + 0] = excl;
  if (base + 1 < N) offsets[base + 1] = excl + v0;
  if (base + 2 < N) offsets[base + 2] = excl + v0 + v1;
  if (base + 3 < N) offsets[base + 3] = excl + v0 + v1 + v2;
}

__global__ __launch_bounds__(256) void scan2_kernel(int* __restrict__ sums, int nb) {
  __shared__ int s[256];
  int t = threadIdx.x;
  int v = (t < nb) ? sums[t] : 0;
  s[t] = v;
  __syncthreads();
  for (int off = 1; off < 256; off <<= 1) {
    int x = (t >= off) ? s[t - off] : 0;
    __syncthreads();
    s[t] += x;
    __syncthreads();
  }
  if (t < nb) sums[t] = s[t] - v;
}

// adds block prefix; also seeds cursor[] (saves a d2d memcpy dispatch)
__global__ __launch_bounds__(256) void scan3_kernel(
    int* __restrict__ offsets, const int* __restrict__ sums,
    int* __restrict__ cursor, int N, int E) {
  int i = blockIdx.x * 256 + threadIdx.x;
  if (i < N) {
    int v = offsets[i] + sums[i >> 10];
    offsets[i] = v;
    cursor[i] = v;
  } else if (i == N) {
    offsets[N] = E;
  }
}

__global__ __launch_bounds__(256) void fill_kernel(
    const int* __restrict__ src, const int* __restrict__ dst,
    int* __restrict__ cursor, int* __restrict__ csr, int E) {
  int e = blockIdx.x * 256 + threadIdx.x;
  if (e >= E) return;
  int d = dst[e];
  int pos = atomicAdd(&cursor[d], 1);
  csr[pos] = src[e];
}

// ---------------- aggregate (bf16 in, f32 acc, bf16 out) ----------------
// One wave per node, split into 4 quarter-waves of 16 lanes.
// Each lane loads uint4 = 8 bf16 feats (16 lanes x 8 = 128 feats/row).
// Quarter q handles edges o0+q, o0+q+4, ... with 2-batched loads -> up to
// 8 independent row fetches in flight per wave (vs 1 in the serial version).
// Cross-quarter reduce: shfl_xor 16/32. Lanes 0..15 write the mean row.
__global__ __launch_bounds__(256) void aggregate_kernel(
    const ushort_t* __restrict__ hb, const int* __restrict__ offsets,
    const int* __restrict__ csr, ushort_t* __restrict__ meanb, int N) {
  int t = threadIdx.x;
  int node = blockIdx.x * 4 + (t >> 6);
  if (node >= N) return;
  int lane = t & 63;
  int grp = lane >> 4;
  int l16 = lane & 15;
  int o0 = offsets[node], o1 = offsets[node + 1];

  float acc[8];
#pragma unroll
  for (int i = 0; i < 8; i++) acc[i] = 0.f;

  int e = o0 + grp;
  // paired iterations: edges e and e+4 fetched concurrently
  for (; e + 4 < o1; e += 8) {
    int s0 = csr[e];
    int s1 = csr[e + 4];
    uint4 v0 = *(const uint4*)&hb[(size_t)s0 * HID + l16 * 8];
    uint4 v1 = *(const uint4*)&hb[(size_t)s1 * HID + l16 * 8];
    acc[0] += bfLo(v0.x) + bfLo(v1.x);
    acc[1] += bfHi(v0.x) + bfHi(v1.x);
    acc[2] += bfLo(v0.y) + bfLo(v1.y);
    acc[3] += bfHi(v0.y) + bfHi(v1.y);
    acc[4] += bfLo(v0.z) + bfLo(v1.z);
    acc[5] += bfHi(v0.z) + bfHi(v1.z);
    acc[6] += bfLo(v0.w) + bfLo(v1.w);
    acc[7] += bfHi(v0.w) + bfHi(v1.w);
  }
  if (e < o1) {
    int s0 = csr[e];
    uint4 v0 = *(const uint4*)&hb[(size_t)s0 * HID + l16 * 8];
    acc[0] += bfLo(v0.x); acc[1] += bfHi(v0.x);
    acc[2] += bfLo(v0.y); acc[3] += bfHi(v0.y);
    acc[4] += bfLo(v0.z); acc[5] += bfHi(v0.z);
    acc[6] += bfLo(v0.w); acc[7] += bfHi(v0.w);
  }

#pragma unroll
  for (int i = 0; i < 8; i++) {
    acc[i] += __shfl_xor(acc[i], 16, 64);
    acc[i] += __shfl_xor(acc[i], 32, 64);
  }

  if (grp == 0) {
    int d = o1 - o0;
    float inv = 1.0f / (float)(d > 1 ? d : 1);
    uint4 p;
    p.x = (uint_t)f2bf(acc[0] * inv) | ((uint_t)f2bf(acc[1] * inv) << 16);
    p.y = (uint_t)f2bf(acc[2] * inv) | ((uint_t)f2bf(acc[3] * inv) << 16);
    p.z = (uint_t)f2bf(acc[4] * inv) | ((uint_t)f2bf(acc[5] * inv) << 16);
    p.w = (uint_t)f2bf(acc[6] * inv) | ((uint_t)f2bf(acc[7] * inv) << 16);
    *(uint4*)&meanb[(size_t)node * HID + l16 * 8] = p;
  }
}

// ---------------- MFMA GEMM: out[r][c] = relu(mean@Wl^T + h@Wr^T + b) ----------------
__global__ __launch_bounds__(256) void mfma_gemm_kernel(
    const ushort_t* __restrict__ meanb, const ushort_t* __restrict__ hb,
    const ushort_t* __restrict__ Wlb, const ushort_t* __restrict__ Wrb,
    const float* __restrict__ bias, float* __restrict__ outF,
    ushort_t* __restrict__ outB, int N, int outIsBf16) {
  const int wave = threadIdx.x >> 6;
  const int lane = threadIdx.x & 63;
  const int rowBase = (blockIdx.x * 4 + wave) * 32;
  if (rowBase >= N) return;
  const int l15 = lane & 15;
  const int quad = lane >> 4;

  int r0 = rowBase + l15;       if (r0 >= N) r0 = N - 1;
  int r1 = rowBase + 16 + l15;  if (r1 >= N) r1 = N - 1;

  f32x4 acc[2][8];
#pragma unroll
  for (int mt = 0; mt < 2; mt++)
#pragma unroll
    for (int nt = 0; nt < 8; nt++) acc[mt][nt] = (f32x4){0.f, 0.f, 0.f, 0.f};

#pragma unroll
  for (int half = 0; half < 2; half++) {
    const ushort_t* A = half ? hb : meanb;
    const ushort_t* W = half ? Wrb : Wlb;
#pragma unroll
    for (int ks = 0; ks < 4; ks++) {
      const int koff = ks * 32 + quad * 8;
      s16x8 a0 = *(const s16x8*)&A[(size_t)r0 * HID + koff];
      s16x8 a1 = *(const s16x8*)&A[(size_t)r1 * HID + koff];
      s16x8 b[8];
#pragma unroll
      for (int nt = 0; nt < 8; nt++)
        b[nt] = *(const s16x8*)&W[(size_t)(nt * 16 + l15) * HID + koff];
#pragma unroll
      for (int nt = 0; nt < 8; nt++) {
        acc[0][nt] = __builtin_amdgcn_mfma_f32_16x16x32_bf16(a0, b[nt], acc[0][nt], 0, 0, 0);
        acc[1][nt] = __builtin_amdgcn_mfma_f32_16x16x32_bf16(a1, b[nt], acc[1][nt], 0, 0, 0);
      }
    }
  }

#pragma unroll
  for (int mt = 0; mt < 2; mt++) {
#pragma unroll
    for (int nt = 0; nt < 8; nt++) {
      int col = nt * 16 + l15;
      float bv = bias[col];
#pragma unroll
      for (int r = 0; r < 4; r++) {
        int row = rowBase + mt * 16 + quad * 4 + r;
        if (row < N) {
          float v = fmaxf(acc[mt][nt][r] + bv, 0.f);
          if (outIsBf16) outB[(size_t)row * HID + col] = f2bf(v);
          else           outF[(size_t)row * HID + col] = v;
        }
      }
    }
  }
}

extern "C" void kernel_launch(void* const* d_in, const int* in_sizes, int n_in,
                              void* d_out, int out_size, void* d_ws, size_t ws_size,
                              hipStream_t stream) {
  const int* x = (const int*)d_in[0];
  const int* ei = (const int*)d_in[1];
  const float* emb = (const float*)d_in[2];
  const float* Wl1 = (const float*)d_in[3];
  const float* bl1 = (const float*)d_in[4];
  const float* Wr1 = (const float*)d_in[5];
  const float* Wl2 = (const float*)d_in[6];
  const float* bl2 = (const float*)d_in[7];
  const float* Wr2 = (const float*)d_in[8];
  float* out = (float*)d_out;

  const int N = in_sizes[0];
  const int E = in_sizes[1] / 2;
  const int* srcI = ei;
  const int* dstI = ei + E;

  // workspace layout
  char* p = (char*)d_ws;
  ushort_t* hb = (ushort_t*)p;    p += (size_t)N * HID * sizeof(ushort_t);
  ushort_t* meanb = (ushort_t*)p; p += (size_t)N * HID * sizeof(ushort_t);
  ushort_t* wb = (ushort_t*)p;    p += (size_t)4 * 16384 * sizeof(ushort_t);
  int* deg = (int*)p;             p += (size_t)((N + 3) & ~3) * sizeof(int);
  int* offsets = (int*)p;         p += (size_t)((N + 4) & ~3) * sizeof(int);
  int* cursor = (int*)p;          p += (size_t)((N + 3) & ~3) * sizeof(int);
  int* csr = (int*)p;             p += (size_t)((E + 3) & ~3) * sizeof(int);
  int* sums = (int*)p;            p += 256 * sizeof(int);

  ushort_t* Wlb1 = wb;
  ushort_t* Wrb1 = wb + 16384;
  ushort_t* Wlb2 = wb + 32768;
  ushort_t* Wrb2 = wb + 49152;

  const int nScanBlocks = (N + 1023) / 1024;  // <=256 required
  const int eBlocks = (E + 255) / 256;
  const int gemmBlocks = (N + 127) / 128;
  const int aggBlocks = (N + 3) / 4;

  // ---- CSR build + conversions ----
  hipMemsetAsync(deg, 0, (size_t)N * sizeof(int), stream);
  wconv_kernel<<<256, 256, 0, stream>>>(Wl1, Wr1, Wl2, Wr2, wb);
  gather_bf16_kernel<<<(N * 32 + 255) / 256, 256, 0, stream>>>(emb, x, hb, N);
  degcount_kernel<<<eBlocks, 256, 0, stream>>>(dstI, deg, E);
  scan1_kernel<<<nScanBlocks, 256, 0, stream>>>(deg, offsets, sums, N);
  scan2_kernel<<<1, 256, 0, stream>>>(sums, nScanBlocks);
  scan3_kernel<<<(N + 256) / 256, 256, 0, stream>>>(offsets, sums, cursor, N, E);
  fill_kernel<<<eBlocks, 256, 0, stream>>>(srcI, dstI, cursor, csr, E);

  // ---- layer 1 ----
  aggregate_kernel<<<aggBlocks, 256, 0, stream>>>(hb, offsets, csr, meanb, N);
  mfma_gemm_kernel<<<gemmBlocks, 256, 0, stream>>>(meanb, hb, Wlb1, Wrb1, bl1,
                                                   nullptr, hb, N, 1);

  // ---- layer 2 ----
  aggregate_kernel<<<aggBlocks, 256, 0, stream>>>(hb, offsets, csr, meanb, N);
  mfma_gemm_kernel<<<gemmBlocks, 256, 0, stream>>>(meanb, hb, Wlb2, Wrb2, bl2,
                                                   out, nullptr, N, 0);
}

// Round 6
// 361.466 us; speedup vs baseline: 6.7521x; 1.0093x over previous
//
#include <hip/hip_runtime.h>

#define HID 128

typedef unsigned short ushort_t;
typedef unsigned int uint_t;
typedef float f32x4 __attribute__((ext_vector_type(4)));
typedef short s16x8 __attribute__((ext_vector_type(8)));

__device__ __forceinline__ ushort_t f2bf(float f) {
  uint_t u = __float_as_uint(f);
  uint_t r = (u + 0x7FFFu + ((u >> 16) & 1u)) >> 16;  // RNE
  return (ushort_t)r;
}
__device__ __forceinline__ float bfLo(uint_t v) { return __uint_as_float(v << 16); }
__device__ __forceinline__ float bfHi(uint_t v) { return __uint_as_float(v & 0xFFFF0000u); }

// ------- fused: hb[i] = bf16(emb[x[i]])  +  weights f32->bf16 -------
// gather occupies the first N*32 threads (N*32 % 256 == 0), wconv the next 65536.
__global__ __launch_bounds__(256) void gather_wconv_kernel(
    const float* __restrict__ emb, const int* __restrict__ x,
    ushort_t* __restrict__ hb, int N,
    const float* __restrict__ Wl1, const float* __restrict__ Wr1,
    const float* __restrict__ Wl2, const float* __restrict__ Wr2,
    ushort_t* __restrict__ wb) {
  int tid = blockIdx.x * 256 + threadIdx.x;
  int gthreads = N * 32;
  if (tid < gthreads) {
    int r = tid >> 5, j = (tid & 31) * 4;
    int s = x[r];
    float4 v = *(const float4*)&emb[(size_t)s * HID + j];
    uint2 p;
    p.x = (uint_t)f2bf(v.x) | ((uint_t)f2bf(v.y) << 16);
    p.y = (uint_t)f2bf(v.z) | ((uint_t)f2bf(v.w) << 16);
    *(uint2*)&hb[(size_t)r * HID + j] = p;
  } else {
    int i = tid - gthreads;
    if (i < 65536) {
      const float* srcs[4] = {Wl1, Wr1, Wl2, Wr2};
      int m = i >> 14, off = i & 16383;
      wb[i] = f2bf(srcs[m][off]);
    }
  }
}

// ---------------- CSR build ----------------
__global__ __launch_bounds__(256) void degcount_kernel(
    const int* __restrict__ dst, int* __restrict__ deg, int E) {
  int e = blockIdx.x * 256 + threadIdx.x;
  if (e < E) atomicAdd(&deg[dst[e]], 1);
}

__global__ __launch_bounds__(256) void scan1_kernel(
    const int* __restrict__ deg, int* __restrict__ offsets,
    int* __restrict__ sums, int N) {
  __shared__ int s[256];
  int b = blockIdx.x, t = threadIdx.x;
  int base = b * 1024 + t * 4;
  int v0 = 0, v1 = 0, v2 = 0, v3 = 0;
  if (base + 0 < N) v0 = deg[base + 0];
  if (base + 1 < N) v1 = deg[base + 1];
  if (base + 2 < N) v2 = deg[base + 2];
  if (base + 3 < N) v3 = deg[base + 3];
  int mySum = v0 + v1 + v2 + v3;
  s[t] = mySum;
  __syncthreads();
  for (int off = 1; off < 256; off <<= 1) {
    int v = (t >= off) ? s[t - off] : 0;
    __syncthreads();
    s[t] += v;
    __syncthreads();
  }
  int excl = s[t] - mySum;
  if (t == 255) sums[b] = s[255];
  if (base + 0 < N) offsets[base + 0] = excl;
  if (base + 1 < N) offsets[base + 1] = excl + v0;
  if (base + 2 < N) offsets[base + 2] = excl + v0 + v1;
  if (base + 3 < N) offsets[base + 3] = excl + v0 + v1 + v2;
}

// adds block prefix (computed in-block from sums[] -> scan2 kernel removed);
// also seeds cursor[]
__global__ __launch_bounds__(256) void scan3_kernel(
    int* __restrict__ offsets, const int* __restrict__ sums,
    int* __restrict__ cursor, int N, int E, int nb) {
  __shared__ int red[256];
  int t = threadIdx.x;
  int chunk = (blockIdx.x * 256) >> 10;  // constant per block (256 | 1024)
  red[t] = (t < chunk) ? sums[t] : 0;    // chunk <= nb <= 256
  __syncthreads();
  for (int off = 128; off > 0; off >>= 1) {
    if (t < off) red[t] += red[t + off];
    __syncthreads();
  }
  int prefix = red[0];
  int i = blockIdx.x * 256 + t;
  if (i < N) {
    int v = offsets[i] + prefix;
    offsets[i] = v;
    cursor[i] = v;
  } else if (i == N) {
    offsets[N] = E;
  }
}

__global__ __launch_bounds__(256) void fill_kernel(
    const int* __restrict__ src, const int* __restrict__ dst,
    int* __restrict__ cursor, int* __restrict__ csr, int E) {
  int e = blockIdx.x * 256 + threadIdx.x;
  if (e >= E) return;
  int d = dst[e];
  int pos = atomicAdd(&cursor[d], 1);
  csr[pos] = src[e];
}

// ---------------- aggregate (bf16 in, f32 acc, bf16 out) ----------------
// One wave per node; 4 quarter-waves x 2-batched loads -> 8 rows in flight.
__global__ __launch_bounds__(256) void aggregate_kernel(
    const ushort_t* __restrict__ hb, const int* __restrict__ offsets,
    const int* __restrict__ csr, ushort_t* __restrict__ meanb, int N) {
  int t = threadIdx.x;
  int node = blockIdx.x * 4 + (t >> 6);
  if (node >= N) return;
  int lane = t & 63;
  int grp = lane >> 4;
  int l16 = lane & 15;
  int o0 = offsets[node], o1 = offsets[node + 1];

  float acc[8];
#pragma unroll
  for (int i = 0; i < 8; i++) acc[i] = 0.f;

  int e = o0 + grp;
  for (; e + 4 < o1; e += 8) {
    int s0 = csr[e];
    int s1 = csr[e + 4];
    uint4 v0 = *(const uint4*)&hb[(size_t)s0 * HID + l16 * 8];
    uint4 v1 = *(const uint4*)&hb[(size_t)s1 * HID + l16 * 8];
    acc[0] += bfLo(v0.x) + bfLo(v1.x);
    acc[1] += bfHi(v0.x) + bfHi(v1.x);
    acc[2] += bfLo(v0.y) + bfLo(v1.y);
    acc[3] += bfHi(v0.y) + bfHi(v1.y);
    acc[4] += bfLo(v0.z) + bfLo(v1.z);
    acc[5] += bfHi(v0.z) + bfHi(v1.z);
    acc[6] += bfLo(v0.w) + bfLo(v1.w);
    acc[7] += bfHi(v0.w) + bfHi(v1.w);
  }
  if (e < o1) {
    int s0 = csr[e];
    uint4 v0 = *(const uint4*)&hb[(size_t)s0 * HID + l16 * 8];
    acc[0] += bfLo(v0.x); acc[1] += bfHi(v0.x);
    acc[2] += bfLo(v0.y); acc[3] += bfHi(v0.y);
    acc[4] += bfLo(v0.z); acc[5] += bfHi(v0.z);
    acc[6] += bfLo(v0.w); acc[7] += bfHi(v0.w);
  }

#pragma unroll
  for (int i = 0; i < 8; i++) {
    acc[i] += __shfl_xor(acc[i], 16, 64);
    acc[i] += __shfl_xor(acc[i], 32, 64);
  }

  if (grp == 0) {
    int d = o1 - o0;
    float inv = 1.0f / (float)(d > 1 ? d : 1);
    uint4 p;
    p.x = (uint_t)f2bf(acc[0] * inv) | ((uint_t)f2bf(acc[1] * inv) << 16);
    p.y = (uint_t)f2bf(acc[2] * inv) | ((uint_t)f2bf(acc[3] * inv) << 16);
    p.z = (uint_t)f2bf(acc[4] * inv) | ((uint_t)f2bf(acc[5] * inv) << 16);
    p.w = (uint_t)f2bf(acc[6] * inv) | ((uint_t)f2bf(acc[7] * inv) << 16);
    *(uint4*)&meanb[(size_t)node * HID + l16 * 8] = p;
  }
}

// ---------------- MFMA GEMM: out = relu(mean@Wl^T + h@Wr^T + b) ----------------
// Wave = 32 rows x 128 cols. Per half, ALL 40 loads (8 A + 32 B) are issued
// into registers before the 64 MFMAs -> ~40 loads in flight per wave
// (vs 10 in the per-ks version; that one measured latency-bound at
// MfmaUtil 3.7%). VGPR ~240 -> 8 waves/CU.
__global__ __launch_bounds__(256) void mfma_gemm_kernel(
    const ushort_t* __restrict__ meanb, const ushort_t* __restrict__ hb,
    const ushort_t* __restrict__ Wlb, const ushort_t* __restrict__ Wrb,
    const float* __restrict__ bias, float* __restrict__ outF,
    ushort_t* __restrict__ outB, int N, int outIsBf16) {
  const int wave = threadIdx.x >> 6;
  const int lane = threadIdx.x & 63;
  const int rowBase = (blockIdx.x * 4 + wave) * 32;
  if (rowBase >= N) return;
  const int l15 = lane & 15;
  const int quad = lane >> 4;
  const int kq = quad * 8;

  int r0 = rowBase + l15;       if (r0 >= N) r0 = N - 1;
  int r1 = rowBase + 16 + l15;  if (r1 >= N) r1 = N - 1;

  f32x4 acc[2][8];
#pragma unroll
  for (int mt = 0; mt < 2; mt++)
#pragma unroll
    for (int nt = 0; nt < 8; nt++) acc[mt][nt] = (f32x4){0.f, 0.f, 0.f, 0.f};

#pragma unroll
  for (int half = 0; half < 2; half++) {
    const ushort_t* A = half ? hb : meanb;
    const ushort_t* W = half ? Wrb : Wlb;
    s16x8 a0[4], a1[4], b[4][8];
#pragma unroll
    for (int ks = 0; ks < 4; ks++) {
      a0[ks] = *(const s16x8*)&A[(size_t)r0 * HID + ks * 32 + kq];
      a1[ks] = *(const s16x8*)&A[(size_t)r1 * HID + ks * 32 + kq];
    }
#pragma unroll
    for (int ks = 0; ks < 4; ks++)
#pragma unroll
      for (int nt = 0; nt < 8; nt++)
        b[ks][nt] = *(const s16x8*)&W[(size_t)(nt * 16 + l15) * HID + ks * 32 + kq];
#pragma unroll
    for (int ks = 0; ks < 4; ks++)
#pragma unroll
      for (int nt = 0; nt < 8; nt++) {
        acc[0][nt] = __builtin_amdgcn_mfma_f32_16x16x32_bf16(a0[ks], b[ks][nt], acc[0][nt], 0, 0, 0);
        acc[1][nt] = __builtin_amdgcn_mfma_f32_16x16x32_bf16(a1[ks], b[ks][nt], acc[1][nt], 0, 0, 0);
      }
  }

#pragma unroll
  for (int mt = 0; mt < 2; mt++) {
#pragma unroll
    for (int nt = 0; nt < 8; nt++) {
      int col = nt * 16 + l15;
      float bv = bias[col];
#pragma unroll
      for (int r = 0; r < 4; r++) {
        int row = rowBase + mt * 16 + quad * 4 + r;
        if (row < N) {
          float v = fmaxf(acc[mt][nt][r] + bv, 0.f);
          if (outIsBf16) outB[(size_t)row * HID + col] = f2bf(v);
          else           outF[(size_t)row * HID + col] = v;
        }
      }
    }
  }
}

extern "C" void kernel_launch(void* const* d_in, const int* in_sizes, int n_in,
                              void* d_out, int out_size, void* d_ws, size_t ws_size,
                              hipStream_t stream) {
  const int* x = (const int*)d_in[0];
  const int* ei = (const int*)d_in[1];
  const float* emb = (const float*)d_in[2];
  const float* Wl1 = (const float*)d_in[3];
  const float* bl1 = (const float*)d_in[4];
  const float* Wr1 = (const float*)d_in[5];
  const float* Wl2 = (const float*)d_in[6];
  const float* bl2 = (const float*)d_in[7];
  const float* Wr2 = (const float*)d_in[8];
  float* out = (float*)d_out;

  const int N = in_sizes[0];
  const int E = in_sizes[1] / 2;
  const int* srcI = ei;
  const int* dstI = ei + E;

  // workspace layout
  char* p = (char*)d_ws;
  ushort_t* hb = (ushort_t*)p;    p += (size_t)N * HID * sizeof(ushort_t);
  ushort_t* meanb = (ushort_t*)p; p += (size_t)N * HID * sizeof(ushort_t);
  ushort_t* wb = (ushort_t*)p;    p += (size_t)4 * 16384 * sizeof(ushort_t);
  int* deg = (int*)p;             p += (size_t)((N + 3) & ~3) * sizeof(int);
  int* offsets = (int*)p;         p += (size_t)((N + 4) & ~3) * sizeof(int);
  int* cursor = (int*)p;          p += (size_t)((N + 3) & ~3) * sizeof(int);
  int* csr = (int*)p;             p += (size_t)((E + 3) & ~3) * sizeof(int);
  int* sums = (int*)p;            p += 256 * sizeof(int);

  ushort_t* Wlb1 = wb;
  ushort_t* Wrb1 = wb + 16384;
  ushort_t* Wlb2 = wb + 32768;
  ushort_t* Wrb2 = wb + 49152;

  const int nScanBlocks = (N + 1023) / 1024;  // <=256 required
  const int eBlocks = (E + 255) / 256;
  const int gemmBlocks = (N + 127) / 128;
  const int aggBlocks = (N + 3) / 4;
  const int gwBlocks = (N * 32 + 65536 + 255) / 256;

  // ---- CSR build + conversions ----
  hipMemsetAsync(deg, 0, (size_t)N * sizeof(int), stream);
  gather_wconv_kernel<<<gwBlocks, 256, 0, stream>>>(emb, x, hb, N,
                                                    Wl1, Wr1, Wl2, Wr2, wb);
  degcount_kernel<<<eBlocks, 256, 0, stream>>>(dstI, deg, E);
  scan1_kernel<<<nScanBlocks, 256, 0, stream>>>(deg, offsets, sums, N);
  scan3_kernel<<<(N + 256) / 256, 256, 0, stream>>>(offsets, sums, cursor,
                                                    N, E, nScanBlocks);
  fill_kernel<<<eBlocks, 256, 0, stream>>>(srcI, dstI, cursor, csr, E);

  // ---- layer 1 ----
  aggregate_kernel<<<aggBlocks, 256, 0, stream>>>(hb, offsets, csr, meanb, N);
  mfma_gemm_kernel<<<gemmBlocks, 256, 0, stream>>>(meanb, hb, Wlb1, Wrb1, bl1,
                                                   nullptr, hb, N, 1);

  // ---- layer 2 ----
  aggregate_kernel<<<aggBlocks, 256, 0, stream>>>(hb, offsets, csr, meanb, N);
  mfma_gemm_kernel<<<gemmBlocks, 256, 0, stream>>>(meanb, hb, Wlb2, Wrb2, bl2,
                                                   out, nullptr, N, 0);
}

// Round 7
// 311.068 us; speedup vs baseline: 7.8461x; 1.1620x over previous
//
#include <hip/hip_runtime.h>

#define HID 128

typedef unsigned short ushort_t;
typedef unsigned int uint_t;
typedef float f32x4 __attribute__((ext_vector_type(4)));
typedef short s16x8 __attribute__((ext_vector_type(8)));

__device__ __forceinline__ ushort_t f2bf(float f) {
  uint_t u = __float_as_uint(f);
  uint_t r = (u + 0x7FFFu + ((u >> 16) & 1u)) >> 16;  // RNE
  return (ushort_t)r;
}
__device__ __forceinline__ float bfLo(uint_t v) { return __uint_as_float(v << 16); }
__device__ __forceinline__ float bfHi(uint_t v) { return __uint_as_float(v & 0xFFFF0000u); }

// ------- fused prep: gather + weight-swizzle + degree count -------
// Thread ranges: [0, N*32) gather; [N*32, N*32+65536) wconv; then E degcount.
// wconv writes weights PRE-SWIZZLED into MFMA B-fragment order:
//   wsw[m][idx], idx = ((ks*8+nt)*64+lane)*8+j  <-  Wm[(nt*16+(lane&15))*128
//                                                    + ks*32 + (lane>>4)*8 + j]
// so the GEMM's LDS reads are contiguous 16B/lane (conflict-free).
__global__ __launch_bounds__(256) void prep_kernel(
    const float* __restrict__ emb, const int* __restrict__ x,
    ushort_t* __restrict__ hb, int N,
    const float* __restrict__ Wl1, const float* __restrict__ Wr1,
    const float* __restrict__ Wl2, const float* __restrict__ Wr2,
    ushort_t* __restrict__ wsw,
    const int* __restrict__ dst, int* __restrict__ deg, int E) {
  int tid = blockIdx.x * 256 + threadIdx.x;
  int gthreads = N * 32;
  if (tid < gthreads) {
    int r = tid >> 5, j = (tid & 31) * 4;
    int s = x[r];
    float4 v = *(const float4*)&emb[(size_t)s * HID + j];
    uint2 p;
    p.x = (uint_t)f2bf(v.x) | ((uint_t)f2bf(v.y) << 16);
    p.y = (uint_t)f2bf(v.z) | ((uint_t)f2bf(v.w) << 16);
    *(uint2*)&hb[(size_t)r * HID + j] = p;
    return;
  }
  tid -= gthreads;
  if (tid < 65536) {
    const float* srcs[4] = {Wl1, Wr1, Wl2, Wr2};
    int m = tid >> 14, idx = tid & 16383;
    int j = idx & 7;
    int lane = (idx >> 3) & 63;
    int nt = (idx >> 9) & 7;
    int ks = (idx >> 12) & 3;
    int row = nt * 16 + (lane & 15);
    int col = ks * 32 + (lane >> 4) * 8 + j;
    wsw[tid] = f2bf(srcs[m][row * HID + col]);
    return;
  }
  tid -= 65536;
  if (tid < E) atomicAdd(&deg[dst[tid]], 1);
}

// ---------------- CSR build ----------------
__global__ __launch_bounds__(256) void scan1_kernel(
    const int* __restrict__ deg, int* __restrict__ offsets,
    int* __restrict__ sums, int N) {
  __shared__ int s[256];
  int b = blockIdx.x, t = threadIdx.x;
  int base = b * 1024 + t * 4;
  int v0 = 0, v1 = 0, v2 = 0, v3 = 0;
  if (base + 0 < N) v0 = deg[base + 0];
  if (base + 1 < N) v1 = deg[base + 1];
  if (base + 2 < N) v2 = deg[base + 2];
  if (base + 3 < N) v3 = deg[base + 3];
  int mySum = v0 + v1 + v2 + v3;
  s[t] = mySum;
  __syncthreads();
  for (int off = 1; off < 256; off <<= 1) {
    int v = (t >= off) ? s[t - off] : 0;
    __syncthreads();
    s[t] += v;
    __syncthreads();
  }
  int excl = s[t] - mySum;
  if (t == 255) sums[b] = s[255];
  if (base + 0 < N) offsets[base + 0] = excl;
  if (base + 1 < N) offsets[base + 1] = excl + v0;
  if (base + 2 < N) offsets[base + 2] = excl + v0 + v1;
  if (base + 3 < N) offsets[base + 3] = excl + v0 + v1 + v2;
}

// adds block prefix (computed in-block from sums[]); also seeds cursor[]
__global__ __launch_bounds__(256) void scan3_kernel(
    int* __restrict__ offsets, const int* __restrict__ sums,
    int* __restrict__ cursor, int N, int E, int nb) {
  __shared__ int red[256];
  int t = threadIdx.x;
  int chunk = (blockIdx.x * 256) >> 10;  // constant per block
  red[t] = (t < chunk) ? sums[t] : 0;
  __syncthreads();
  for (int off = 128; off > 0; off >>= 1) {
    if (t < off) red[t] += red[t + off];
    __syncthreads();
  }
  int prefix = red[0];
  int i = blockIdx.x * 256 + t;
  if (i < N) {
    int v = offsets[i] + prefix;
    offsets[i] = v;
    cursor[i] = v;
  } else if (i == N) {
    offsets[N] = E;
  }
}

__global__ __launch_bounds__(256) void fill_kernel(
    const int* __restrict__ src, const int* __restrict__ dst,
    int* __restrict__ cursor, int* __restrict__ csr, int E) {
  int e = blockIdx.x * 256 + threadIdx.x;
  if (e >= E) return;
  int d = dst[e];
  int pos = atomicAdd(&cursor[d], 1);
  csr[pos] = src[e];
}

// ---------------- aggregate (bf16 in, f32 acc, bf16 out) ----------------
// One wave per node; 4 quarter-waves x 2-batched loads -> 8 rows in flight.
__global__ __launch_bounds__(256) void aggregate_kernel(
    const ushort_t* __restrict__ hb, const int* __restrict__ offsets,
    const int* __restrict__ csr, ushort_t* __restrict__ meanb, int N) {
  int t = threadIdx.x;
  int node = blockIdx.x * 4 + (t >> 6);
  if (node >= N) return;
  int lane = t & 63;
  int grp = lane >> 4;
  int l16 = lane & 15;
  int o0 = offsets[node], o1 = offsets[node + 1];

  float acc[8];
#pragma unroll
  for (int i = 0; i < 8; i++) acc[i] = 0.f;

  int e = o0 + grp;
  for (; e + 4 < o1; e += 8) {
    int s0 = csr[e];
    int s1 = csr[e + 4];
    uint4 v0 = *(const uint4*)&hb[(size_t)s0 * HID + l16 * 8];
    uint4 v1 = *(const uint4*)&hb[(size_t)s1 * HID + l16 * 8];
    acc[0] += bfLo(v0.x) + bfLo(v1.x);
    acc[1] += bfHi(v0.x) + bfHi(v1.x);
    acc[2] += bfLo(v0.y) + bfLo(v1.y);
    acc[3] += bfHi(v0.y) + bfHi(v1.y);
    acc[4] += bfLo(v0.z) + bfLo(v1.z);
    acc[5] += bfHi(v0.z) + bfHi(v1.z);
    acc[6] += bfLo(v0.w) + bfLo(v1.w);
    acc[7] += bfHi(v0.w) + bfHi(v1.w);
  }
  if (e < o1) {
    int s0 = csr[e];
    uint4 v0 = *(const uint4*)&hb[(size_t)s0 * HID + l16 * 8];
    acc[0] += bfLo(v0.x); acc[1] += bfHi(v0.x);
    acc[2] += bfLo(v0.y); acc[3] += bfHi(v0.y);
    acc[4] += bfLo(v0.z); acc[5] += bfHi(v0.z);
    acc[6] += bfLo(v0.w); acc[7] += bfHi(v0.w);
  }

#pragma unroll
  for (int i = 0; i < 8; i++) {
    acc[i] += __shfl_xor(acc[i], 16, 64);
    acc[i] += __shfl_xor(acc[i], 32, 64);
  }

  if (grp == 0) {
    int d = o1 - o0;
    float inv = 1.0f / (float)(d > 1 ? d : 1);
    uint4 p;
    p.x = (uint_t)f2bf(acc[0] * inv) | ((uint_t)f2bf(acc[1] * inv) << 16);
    p.y = (uint_t)f2bf(acc[2] * inv) | ((uint_t)f2bf(acc[3] * inv) << 16);
    p.z = (uint_t)f2bf(acc[4] * inv) | ((uint_t)f2bf(acc[5] * inv) << 16);
    p.w = (uint_t)f2bf(acc[6] * inv) | ((uint_t)f2bf(acc[7] * inv) << 16);
    *(uint4*)&meanb[(size_t)node * HID + l16 * 8] = p;
  }
}

// ---------------- MFMA GEMM: out = relu(mean@Wl^T + h@Wr^T + b) ----------------
// Weights (pre-swizzled to B-frag order) staged in LDS: 64 KB/block.
// Inner loop: ds_read_b128 at lane*16 contiguous (conflict-free) + MFMA.
// A-frags: 16 global loads issued BEFORE the barrier (prefetch).
// R6 lesson: compiler won't hold 32 global B-frags in VGPRs (VGPR_Count=76,
// loads sunk next to MFMAs -> 200-cyc L2 serialization, MfmaUtil 3.7%).
__global__ __launch_bounds__(256) void mfma_gemm_kernel(
    const ushort_t* __restrict__ meanb, const ushort_t* __restrict__ hb,
    const ushort_t* __restrict__ WlS, const ushort_t* __restrict__ WrS,
    const float* __restrict__ bias, float* __restrict__ outF,
    ushort_t* __restrict__ outB, int N, int outIsBf16) {
  __shared__ ushort_t ws[32768];  // 64 KB: [0..16383]=Wl frags, rest = Wr
  const int t = threadIdx.x;
  const int wave = t >> 6;
  const int lane = t & 63;
  const int rowBase = (blockIdx.x * 4 + wave) * 32;
  const int l15 = lane & 15;
  const int quad = lane >> 4;
  const int kq = quad * 8;
  const bool active = rowBase < N;

  int r0 = rowBase + l15;       if (r0 >= N) r0 = N - 1;
  int r1 = rowBase + 16 + l15;  if (r1 >= N) r1 = N - 1;

  // A-frag prefetch (independent of LDS staging)
  s16x8 a[2][2][4];  // [half][rowgrp][ks]
  if (active) {
#pragma unroll
    for (int ks = 0; ks < 4; ks++) {
      a[0][0][ks] = *(const s16x8*)&meanb[(size_t)r0 * HID + ks * 32 + kq];
      a[0][1][ks] = *(const s16x8*)&meanb[(size_t)r1 * HID + ks * 32 + kq];
      a[1][0][ks] = *(const s16x8*)&hb[(size_t)r0 * HID + ks * 32 + kq];
      a[1][1][ks] = *(const s16x8*)&hb[(size_t)r1 * HID + ks * 32 + kq];
    }
  }

  // stage both weight matrices: contiguous 16B per thread, coalesced
#pragma unroll
  for (int it = 0; it < 8; it++) {
    int o = (it * 256 + t) * 8;
    *(s16x8*)&ws[o] = *(const s16x8*)&WlS[o];
    *(s16x8*)&ws[16384 + o] = *(const s16x8*)&WrS[o];
  }
  __syncthreads();

  if (active) {
    f32x4 acc[2][8];
#pragma unroll
    for (int mt = 0; mt < 2; mt++)
#pragma unroll
      for (int nt = 0; nt < 8; nt++) acc[mt][nt] = (f32x4){0.f, 0.f, 0.f, 0.f};

#pragma unroll
    for (int half = 0; half < 2; half++) {
      const int hbase = half * 16384;
#pragma unroll
      for (int ks = 0; ks < 4; ks++)
#pragma unroll
        for (int nt = 0; nt < 8; nt++) {
          s16x8 b = *(const s16x8*)&ws[hbase + ((ks * 8 + nt) * 64 + lane) * 8];
          acc[0][nt] = __builtin_amdgcn_mfma_f32_16x16x32_bf16(a[half][0][ks], b, acc[0][nt], 0, 0, 0);
          acc[1][nt] = __builtin_amdgcn_mfma_f32_16x16x32_bf16(a[half][1][ks], b, acc[1][nt], 0, 0, 0);
        }
    }

#pragma unroll
    for (int mt = 0; mt < 2; mt++) {
#pragma unroll
      for (int nt = 0; nt < 8; nt++) {
        int col = nt * 16 + l15;
        float bv = bias[col];
#pragma unroll
        for (int r = 0; r < 4; r++) {
          int row = rowBase + mt * 16 + quad * 4 + r;
          if (row < N) {
            float v = fmaxf(acc[mt][nt][r] + bv, 0.f);
            if (outIsBf16) outB[(size_t)row * HID + col] = f2bf(v);
            else           outF[(size_t)row * HID + col] = v;
          }
        }
      }
    }
  }
}

extern "C" void kernel_launch(void* const* d_in, const int* in_sizes, int n_in,
                              void* d_out, int out_size, void* d_ws, size_t ws_size,
                              hipStream_t stream) {
  const int* x = (const int*)d_in[0];
  const int* ei = (const int*)d_in[1];
  const float* emb = (const float*)d_in[2];
  const float* Wl1 = (const float*)d_in[3];
  const float* bl1 = (const float*)d_in[4];
  const float* Wr1 = (const float*)d_in[5];
  const float* Wl2 = (const float*)d_in[6];
  const float* bl2 = (const float*)d_in[7];
  const float* Wr2 = (const float*)d_in[8];
  float* out = (float*)d_out;

  const int N = in_sizes[0];
  const int E = in_sizes[1] / 2;
  const int* srcI = ei;
  const int* dstI = ei + E;

  // workspace layout
  char* p = (char*)d_ws;
  ushort_t* hb = (ushort_t*)p;    p += (size_t)N * HID * sizeof(ushort_t);
  ushort_t* meanb = (ushort_t*)p; p += (size_t)N * HID * sizeof(ushort_t);
  ushort_t* wb = (ushort_t*)p;    p += (size_t)4 * 16384 * sizeof(ushort_t);
  int* deg = (int*)p;             p += (size_t)((N + 3) & ~3) * sizeof(int);
  int* offsets = (int*)p;         p += (size_t)((N + 4) & ~3) * sizeof(int);
  int* cursor = (int*)p;          p += (size_t)((N + 3) & ~3) * sizeof(int);
  int* csr = (int*)p;             p += (size_t)((E + 3) & ~3) * sizeof(int);
  int* sums = (int*)p;            p += 256 * sizeof(int);

  ushort_t* Wlb1 = wb;
  ushort_t* Wrb1 = wb + 16384;
  ushort_t* Wlb2 = wb + 32768;
  ushort_t* Wrb2 = wb + 49152;

  const int nScanBlocks = (N + 1023) / 1024;  // <=256 required
  const int eBlocks = (E + 255) / 256;
  const int gemmBlocks = (N + 127) / 128;
  const int aggBlocks = (N + 3) / 4;
  const int prepBlocks = (N * 32 + 65536 + E + 255) / 256;

  // ---- CSR build + conversions ----
  hipMemsetAsync(deg, 0, (size_t)N * sizeof(int), stream);
  prep_kernel<<<prepBlocks, 256, 0, stream>>>(emb, x, hb, N,
                                              Wl1, Wr1, Wl2, Wr2, wb,
                                              dstI, deg, E);
  scan1_kernel<<<nScanBlocks, 256, 0, stream>>>(deg, offsets, sums, N);
  scan3_kernel<<<(N + 256) / 256, 256, 0, stream>>>(offsets, sums, cursor,
                                                    N, E, nScanBlocks);
  fill_kernel<<<eBlocks, 256, 0, stream>>>(srcI, dstI, cursor, csr, E);

  // ---- layer 1 ----
  aggregate_kernel<<<aggBlocks, 256, 0, stream>>>(hb, offsets, csr, meanb, N);
  mfma_gemm_kernel<<<gemmBlocks, 256, 0, stream>>>(meanb, hb, Wlb1, Wrb1, bl1,
                                                   nullptr, hb, N, 1);

  // ---- layer 2 ----
  aggregate_kernel<<<aggBlocks, 256, 0, stream>>>(hb, offsets, csr, meanb, N);
  mfma_gemm_kernel<<<gemmBlocks, 256, 0, stream>>>(meanb, hb, Wlb2, Wrb2, bl2,
                                                   out, nullptr, N, 0);
}